// Round 2
// baseline (98.838 us; speedup 1.0000x reference)
//
#include <hip/hip_runtime.h>
#include <hip/hip_fp16.h>
#include <math.h>

// EPG GRE F0, NP2=64 pulses, V voxels.
// 16 lanes per voxel-pair: lane sub (0..15) holds levels k0=sub (slot0),
// k1=16+sub (slot1) for TWO voxels packed in the f16 halves of each 32-bit reg
// (voxA = lo half, voxB = hi half). v_pk_fma_f16 = 2x the f32 pipe rate.
// ROUND 21: kill the per-iteration lgkmcnt(0) stall.
// R19/R20 both pinned at VALUBusy ~54% regardless of waves/ILP -> fixed
// per-iteration stall. Diagnosis: cwq[nb] is provably uniform -> s_load
// (SMEM). SMEM+DS share lgkmcnt and SMEM completes out-of-order vs DS, so
// consuming the coefficients forces s_waitcnt lgkmcnt(0) -> drains the
// per-pulse F0 ds_writes every iteration. Fix: launder the coef index
// through a runtime zero (cw[527]) * (1+tid) so the address lives in a
// VGPR the compiler cannot prove uniform -> global_load_dwordx4 (vmcnt,
// decoupled from DS). Prefetch distance 2 covers L2 latency. Math is
// op-for-op identical to the passing R20 kernel.
// Rz-factorized RF (R11) with deferred relax, 3-phase live-cone (R14).
// Phases: A p<15 slot0 only; B 15..47 both slots; C 48..63 slot0 only.

#define NP2 64
#define ROR1  0x121   // row_ror:1 : dest lane i <- lane (i-1) & 15   (P: k <- k-1)
#define ROR15 0x12F   // row_ror:15: dest lane i <- lane (i+1) & 15   (M: k <- k+1)
#define RSHL1 0x101   // row_shl:1 : dest lane i <- lane i+1; lane15 <- 0 (bound_ctrl)

__device__ __forceinline__ unsigned h2u(__half2 x) {
    unsigned u; __builtin_memcpy(&u, &x, 4); return u;
}
__device__ __forceinline__ __half2 u2h(unsigned u) {
    __half2 h; __builtin_memcpy(&h, &u, 4); return h;
}
template<int CTRL>
__device__ __forceinline__ __half2 rroth(__half2 x) {
    return u2h((unsigned)__builtin_amdgcn_mov_dpp((int)h2u(x), CTRL, 0xF, 0xF, true));
}

// ---- pre-kernel: coefficient table [65][8] uints + 8 pad uints in d_ws ----
// row p: [cd sd ca2 sa2 sa ca h 0], each uint = duplicated f16 pair.
// cd+i*sd = e^{i(phi_{p-1}-phi_p)} from unit vectors; phi_{-1}=0.
// uints 512..527 = zero pad (prefetch target + laundering zero at [527]).
__global__ void coef_kernel(const float* __restrict__ theta_re,
                            const float* __restrict__ theta_im,
                            unsigned* __restrict__ cw)
{
    const int t = threadIdx.x;
    if (t < NP2) {
        const float tre = theta_re[t], tim = theta_im[t];
        const float a2 = tre * tre + tim * tim;
        const float inva = __frsqrt_rn(a2);        // |theta| >= 0.1
        const float a = a2 * inva;
        const float c = tre * inva, s = tim * inva;   // cos/sin(phi_p)
        float cp = 1.f, sp = 0.f;                     // cos/sin(phi_{p-1})
        if (t > 0) {
            const float ure = theta_re[t - 1], uim = theta_im[t - 1];
            const float ia = __frsqrt_rn(ure * ure + uim * uim);
            cp = ure * ia; sp = uim * ia;
        }
        const float cd = cp * c + sp * s;          // cos(phi_{p-1}-phi_p)
        const float sd = sp * c - cp * s;          // sin(phi_{p-1}-phi_p)
        float sa, ca;
        __sincosf(a, &sa, &ca);
        const float ca2 = 0.5f + 0.5f * ca;        // cos^2(a/2)
        const float sa2 = 0.5f - 0.5f * ca;        // sin^2(a/2)
        unsigned* row = cw + t * 8;
        const float vals[8] = { cd, sd, ca2, sa2, sa, ca, 0.5f * sa, 0.f };
        for (int j = 0; j < 8; ++j) {
            const __half h = __float2half(vals[j]);
            __half2 hp = __halves2half2(h, h);
            unsigned u; __builtin_memcpy(&u, &hp, 4);
            row[j] = u;
        }
    } else if (t < NP2 + 16) {
        cw[NP2 * 8 + (t - NP2)] = 0u;              // zero pad rows 64,65 (prefetch + launder)
    }
}

// one slot's matvec (both voxels via f16 halves); outputs unshifted nP/nM, updates Z
__device__ __forceinline__ void slot_mat(
    __half2 Pr, __half2 Pi, __half2 Mr, __half2 Mi, __half2& Zr, __half2& Zi,
    __half2 ec, __half2 es, __half2 esn,
    __half2 ca2, __half2 sa2, __half2 sa, __half2 ca, __half2 hh,
    __half2 pE1, __half2 rec,
    __half2& nPr, __half2& nPi, __half2& nMr, __half2& nMi)
{
    const __half2 hPr = __hfma2(ec, Pr, __hmul2(esn, Pi));
    const __half2 hPi = __hfma2(ec, Pi, __hmul2(es,  Pr));
    const __half2 hMr = __hfma2(ec, Mr, __hmul2(es,  Mi));
    const __half2 hMi = __hfma2(ec, Mi, __hmul2(esn, Mr));
    const __half2 ezr = __hfma2(pE1, Zr, rec);
    const __half2 ezi = __hmul2(pE1, Zi);
    const __half2 szr = __hmul2(sa, ezr);
    const __half2 szi = __hmul2(sa, ezi);
    const __half2 szrn = __hneg2(szr);
    const __half2 szin = __hneg2(szi);
    nPr = __hfma2(ca2, hPr, __hfma2(sa2, hMr, szi));
    nPi = __hfma2(ca2, hPi, __hfma2(sa2, hMi, szrn));
    nMr = __hfma2(sa2, hPr, __hfma2(ca2, hMr, szin));
    nMi = __hfma2(sa2, hPi, __hfma2(ca2, hMi, szr));
    Zr = __hfma2(hh, __hsub2(hPi, hMi), __hmul2(ca, ezr));
    Zi = __hfma2(hh, __hsub2(hMr, hPr), __hmul2(ca, ezi));
}

__global__ __launch_bounds__(256, 4) void epg_kernel(
    const float* __restrict__ TRp,
    const float* __restrict__ qmaps,
    const unsigned* __restrict__ cw,
    float* __restrict__ out, int V)
{
    const int t = threadIdx.x;
    const int sub = t & 15;           // lane within voxel group
    const int vloc = t >> 4;          // 0..15
    const int base = blockIdx.x * 64;
    const int vA = base + vloc;       // pair-a lo f16 half
    const int vB = vA + 16;           // pair-a hi f16 half
    const int vC = vA + 32;           // pair-b lo f16 half
    const int vD = vA + 48;           // pair-b hi f16 half

    __shared__ unsigned bufPrA[16][65], bufPiA[16][65];  // pair-a packed F~0, +1 pad
    __shared__ unsigned bufPrB[16][65], bufPiB[16][65];  // pair-b packed F~0

    const float tr = TRp[0];
    const float E1A = __expf(-tr / qmaps[V + vA]);
    const float E2A = __expf(-tr / qmaps[2 * V + vA]);
    const float E1B = __expf(-tr / qmaps[V + vB]);
    const float E2B = __expf(-tr / qmaps[2 * V + vB]);
    const float E1C = __expf(-tr / qmaps[V + vC]);
    const float E2C = __expf(-tr / qmaps[2 * V + vC]);
    const float E1D = __expf(-tr / qmaps[V + vD]);
    const float E2D = __expf(-tr / qmaps[2 * V + vD]);
    const bool s0 = (sub == 0);
    const bool s15 = (sub == 15);
    const __half2 pE1a = __floats2half2_rn(E1A, E1B);
    const __half2 pE2a = __floats2half2_rn(E2A, E2B);
    const __half2 pE1b = __floats2half2_rn(E1C, E1D);
    const __half2 pE2b = __floats2half2_rn(E2C, E2D);
    const __half2 zeroH = __floats2half2_rn(0.f, 0.f);
    const __half2 recHa = s0 ? __floats2half2_rn(1.f - E1A, 1.f - E1B) : zeroH;
    const __half2 recHb = s0 ? __floats2half2_rn(1.f - E1C, 1.f - E1D) : zeroH;

    // slot-packed state, 2 voxels per reg (f16 halves), two independent pairs
    __half2 Pr0a = zeroH, Pr1a = zeroH, Pi0a = zeroH, Pi1a = zeroH;
    __half2 Mr0a = zeroH, Mr1a = zeroH, Mi0a = zeroH, Mi1a = zeroH;
    __half2 Zr0a = s0 ? __floats2half2_rn(1.f, 1.f) : zeroH;   // E1*1+(1-E1)=1 exact
    __half2 Zr1a = zeroH, Zi0a = zeroH, Zi1a = zeroH;
    __half2 Pr0b = zeroH, Pr1b = zeroH, Pi0b = zeroH, Pi1b = zeroH;
    __half2 Mr0b = zeroH, Mr1b = zeroH, Mi0b = zeroH, Mi1b = zeroH;
    __half2 Zr0b = s0 ? __floats2half2_rn(1.f, 1.f) : zeroH;
    __half2 Zr1b = zeroH, Zi0b = zeroH, Zi1b = zeroH;

    // coefficient stream: laundered index forces VMEM (vmcnt) loads that the
    // compiler cannot scalarize to SMEM -> no lgkmcnt waits in the loop.
    // lz == 0 at runtime (cw[527] is zeroed) but is unprovable at compile time.
    const unsigned lz = cw[NP2 * 8 + 15] * (1u + (unsigned)t);
    const uint4* __restrict__ cwq = (const uint4*)cw;
    uint4 c0 = cwq[lz + 0], c1 = cwq[lz + 1];      // iter p coeffs
    uint4 n0 = cwq[lz + 2], n1 = cwq[lz + 3];      // iter p+1 coeffs

    __half2 nPr0a, nPi0a, nMr0a, nMi0a, nPr1a, nPi1a, nMr1a, nMi1a;
    __half2 nPr0b, nPi0b, nMr0b, nMi0b, nPr1b, nPi1b, nMr1b, nMi1b;

    // ---- phase A: p in [0,15), slot1 exactly zero -> slot0 only ----
#pragma unroll 1
    for (int p = 0; p < 15; ++p) {
        const int nb = 2 * (p + 2);
        const uint4 f0 = cwq[lz + nb], f1 = cwq[lz + nb + 1];   // prefetch p+2
        const __half2 cd = u2h(c0.x), sd = u2h(c0.y);
        const __half2 ca2 = u2h(c0.z), sa2 = u2h(c0.w);
        const __half2 sa = u2h(c1.x), ca = u2h(c1.y), hh = u2h(c1.z);
        const __half2 eca = __hmul2(pE2a, cd);
        const __half2 esa = __hmul2(pE2a, sd);
        const __half2 esna = __hneg2(esa);
        const __half2 ecb = __hmul2(pE2b, cd);
        const __half2 esb = __hmul2(pE2b, sd);
        const __half2 esnb = __hneg2(esb);
        slot_mat(Pr0a, Pi0a, Mr0a, Mi0a, Zr0a, Zi0a, eca, esa, esna,
                 ca2, sa2, sa, ca, hh, pE1a, recHa, nPr0a, nPi0a, nMr0a, nMi0a);
        slot_mat(Pr0b, Pi0b, Mr0b, Mi0b, Zr0b, Zi0b, ecb, esb, esnb,
                 ca2, sa2, sa, ca, hh, pE1b, recHb, nPr0b, nPi0b, nMr0b, nMi0b);
        if (s0) {
            bufPrA[vloc][p] = h2u(nPr0a); bufPiA[vloc][p] = h2u(nPi0a);
            bufPrB[vloc][p] = h2u(nPr0b); bufPiB[vloc][p] = h2u(nPi0b);
        }
        const __half2 rPra = rroth<ROR1>(nPr0a);
        const __half2 rPia = rroth<ROR1>(nPi0a);
        const __half2 rMra = rroth<RSHL1>(nMr0a);  // lane i <- i+1; lane15 <- 0
        const __half2 rMia = rroth<RSHL1>(nMi0a);
        const __half2 rPrb = rroth<ROR1>(nPr0b);
        const __half2 rPib = rroth<ROR1>(nPi0b);
        const __half2 rMrb = rroth<RSHL1>(nMr0b);
        const __half2 rMib = rroth<RSHL1>(nMi0b);
        Pr0a = s0 ? rMra : rPra;                   // level0 <- conj(M'_1)
        Pi0a = s0 ? __hneg2(rMia) : rPia;
        Mr0a = rMra;                               // lane15: 0 (exact: M'_16 = 0)
        Mi0a = rMia;
        Pr0b = s0 ? rMrb : rPrb;
        Pi0b = s0 ? __hneg2(rMib) : rPib;
        Mr0b = rMrb;
        Mi0b = rMib;
        c0 = n0; c1 = n1; n0 = f0; n1 = f1;
    }

    // ---- phase B: p in [15,48), both slots live ----
#pragma unroll 1
    for (int p = 15; p < 48; ++p) {
        const int nb = 2 * (p + 2);
        const uint4 f0 = cwq[lz + nb], f1 = cwq[lz + nb + 1];   // prefetch p+2
        const __half2 cd = u2h(c0.x), sd = u2h(c0.y);
        const __half2 ca2 = u2h(c0.z), sa2 = u2h(c0.w);
        const __half2 sa = u2h(c1.x), ca = u2h(c1.y), hh = u2h(c1.z);
        const __half2 eca = __hmul2(pE2a, cd);
        const __half2 esa = __hmul2(pE2a, sd);
        const __half2 esna = __hneg2(esa);
        const __half2 ecb = __hmul2(pE2b, cd);
        const __half2 esb = __hmul2(pE2b, sd);
        const __half2 esnb = __hneg2(esb);
        slot_mat(Pr0a, Pi0a, Mr0a, Mi0a, Zr0a, Zi0a, eca, esa, esna,
                 ca2, sa2, sa, ca, hh, pE1a, recHa, nPr0a, nPi0a, nMr0a, nMi0a);
        slot_mat(Pr1a, Pi1a, Mr1a, Mi1a, Zr1a, Zi1a, eca, esa, esna,
                 ca2, sa2, sa, ca, hh, pE1a, zeroH, nPr1a, nPi1a, nMr1a, nMi1a);
        slot_mat(Pr0b, Pi0b, Mr0b, Mi0b, Zr0b, Zi0b, ecb, esb, esnb,
                 ca2, sa2, sa, ca, hh, pE1b, recHb, nPr0b, nPi0b, nMr0b, nMi0b);
        slot_mat(Pr1b, Pi1b, Mr1b, Mi1b, Zr1b, Zi1b, ecb, esb, esnb,
                 ca2, sa2, sa, ca, hh, pE1b, zeroH, nPr1b, nPi1b, nMr1b, nMi1b);
        if (s0) {
            bufPrA[vloc][p] = h2u(nPr0a); bufPiA[vloc][p] = h2u(nPi0a);
            bufPrB[vloc][p] = h2u(nPr0b); bufPiB[vloc][p] = h2u(nPi0b);
        }
        const __half2 rPr0a = rroth<ROR1>(nPr0a),  rPr1a = rroth<ROR1>(nPr1a);
        const __half2 rPi0a = rroth<ROR1>(nPi0a),  rPi1a = rroth<ROR1>(nPi1a);
        const __half2 rMr0a = rroth<ROR15>(nMr0a), rMr1a = rroth<ROR15>(nMr1a);
        const __half2 rMi0a = rroth<ROR15>(nMi0a), rMi1a = rroth<ROR15>(nMi1a);
        const __half2 rPr0b = rroth<ROR1>(nPr0b),  rPr1b = rroth<ROR1>(nPr1b);
        const __half2 rPi0b = rroth<ROR1>(nPi0b),  rPi1b = rroth<ROR1>(nPi1b);
        const __half2 rMr0b = rroth<ROR15>(nMr0b), rMr1b = rroth<ROR15>(nMr1b);
        const __half2 rMi0b = rroth<ROR15>(nMi0b), rMi1b = rroth<ROR15>(nMi1b);
        Pr1a = s0 ? rPr0a : rPr1a;                 // level16 <- P'_15
        Pi1a = s0 ? rPi0a : rPi1a;
        Pr0a = s0 ? rMr0a : rPr0a;                 // level0 <- conj(M'_1)
        Pi0a = s0 ? __hneg2(rMi0a) : rPi0a;
        Mr0a = s15 ? rMr1a : rMr0a;                // level15 <- M'_16
        Mi0a = s15 ? rMi1a : rMi0a;
        Mr1a = s15 ? zeroH : rMr1a;                // level31 <- M'_32 = 0 exactly
        Mi1a = s15 ? zeroH : rMi1a;
        Pr1b = s0 ? rPr0b : rPr1b;
        Pi1b = s0 ? rPi0b : rPi1b;
        Pr0b = s0 ? rMr0b : rPr0b;
        Pi0b = s0 ? __hneg2(rMi0b) : rPi0b;
        Mr0b = s15 ? rMr1b : rMr0b;
        Mi0b = s15 ? rMi1b : rMi0b;
        Mr1b = s15 ? zeroH : rMr1b;
        Mi1b = s15 ? zeroH : rMi1b;
        c0 = n0; c1 = n1; n0 = f0; n1 = f1;
    }

    // ---- phase C: p in [48,64), slot1 in the dead cone -> slot0 only ----
#pragma unroll 1
    for (int p = 48; p < NP2; ++p) {
        const int nb = 2 * (p + 2);
        const uint4 f0 = cwq[lz + nb], f1 = cwq[lz + nb + 1];   // prefetch (pad rows at end)
        const __half2 cd = u2h(c0.x), sd = u2h(c0.y);
        const __half2 ca2 = u2h(c0.z), sa2 = u2h(c0.w);
        const __half2 sa = u2h(c1.x), ca = u2h(c1.y), hh = u2h(c1.z);
        const __half2 eca = __hmul2(pE2a, cd);
        const __half2 esa = __hmul2(pE2a, sd);
        const __half2 esna = __hneg2(esa);
        const __half2 ecb = __hmul2(pE2b, cd);
        const __half2 esb = __hmul2(pE2b, sd);
        const __half2 esnb = __hneg2(esb);
        slot_mat(Pr0a, Pi0a, Mr0a, Mi0a, Zr0a, Zi0a, eca, esa, esna,
                 ca2, sa2, sa, ca, hh, pE1a, recHa, nPr0a, nPi0a, nMr0a, nMi0a);
        slot_mat(Pr0b, Pi0b, Mr0b, Mi0b, Zr0b, Zi0b, ecb, esb, esnb,
                 ca2, sa2, sa, ca, hh, pE1b, recHb, nPr0b, nPi0b, nMr0b, nMi0b);
        if (s0) {
            bufPrA[vloc][p] = h2u(nPr0a); bufPiA[vloc][p] = h2u(nPi0a);
            bufPrB[vloc][p] = h2u(nPr0b); bufPiB[vloc][p] = h2u(nPi0b);
        }
        const __half2 rPra = rroth<ROR1>(nPr0a);
        const __half2 rPia = rroth<ROR1>(nPi0a);
        const __half2 rMra = rroth<RSHL1>(nMr0a);  // lane15's junk: dead cone
        const __half2 rMia = rroth<RSHL1>(nMi0a);
        const __half2 rPrb = rroth<ROR1>(nPr0b);
        const __half2 rPib = rroth<ROR1>(nPi0b);
        const __half2 rMrb = rroth<RSHL1>(nMr0b);
        const __half2 rMib = rroth<RSHL1>(nMi0b);
        Pr0a = s0 ? rMra : rPra;
        Pi0a = s0 ? __hneg2(rMia) : rPia;
        Mr0a = rMra;
        Mi0a = rMia;
        Pr0b = s0 ? rMrb : rPrb;
        Pi0b = s0 ? __hneg2(rMib) : rPib;
        Mr0b = rMrb;
        Mi0b = rMib;
        c0 = n0; c1 = n1; n0 = f0; n1 = f1;
    }

    // ---- epilogue: unpack f16 halves, magnitude * PD (f32), coalesced stores ----
    __syncthreads();
    float4* out4 = (float4*)out;
#pragma unroll
    for (int i = 0; i < 4; ++i) {
        const int q = i * 256 + t;
        const int r = q >> 4;              // output voxel row 0..63
        const int c = (q & 15) * 4;        // pulse col
        const int row = r & 15;            // state row
        const bool hi = (r >> 4) & 1;      // which f16 half
        const bool pb = (r >> 5) & 1;      // which pair buffer
        const float PDr = qmaps[base + r];
        float4 val;
        float* vp = &val.x;
#pragma unroll
        for (int j = 0; j < 4; ++j) {
            const unsigned ur = pb ? bufPrB[row][c + j] : bufPrA[row][c + j];
            const unsigned ui = pb ? bufPiB[row][c + j] : bufPiA[row][c + j];
            const __half2 hr = u2h(ur);
            const __half2 hii = u2h(ui);
            const float pr = hi ? __high2float(hr) : __low2float(hr);
            const float pi = hi ? __high2float(hii) : __low2float(hii);
            vp[j] = sqrtf(pr * pr + pi * pi) * PDr;
        }
        out4[blockIdx.x * 1024 + q] = val;
    }
}

extern "C" void kernel_launch(void* const* d_in, const int* in_sizes, int n_in,
                              void* d_out, int out_size, void* d_ws, size_t ws_size,
                              hipStream_t stream) {
    const float* theta_re = (const float*)d_in[0];
    const float* theta_im = (const float*)d_in[1];
    const float* TRp      = (const float*)d_in[2];
    const float* qmaps    = (const float*)d_in[3];
    float* out = (float*)d_out;
    unsigned* cw = (unsigned*)d_ws;            // [66][8] uints = 2112 B (rows 64,65 = pad)
    const int V = in_sizes[3] / 3;             // qmaps is [3, V, 1]
    coef_kernel<<<dim3(1), dim3(128), 0, stream>>>(theta_re, theta_im, cw);
    epg_kernel<<<dim3(V / 64), dim3(256), 0, stream>>>(TRp, qmaps, cw, out, V);
}

// Round 4
// 96.033 us; speedup vs baseline: 1.0292x; 1.0292x over previous
//
#include <hip/hip_runtime.h>
#include <hip/hip_fp16.h>
#include <math.h>

// EPG GRE F0, NP2=64 pulses, V voxels.
// 16 lanes per voxel-pair: lane sub (0..15) holds levels k0=sub (slot0),
// k1=16+sub (slot1) for TWO voxels packed in the f16 halves of each 32-bit reg
// (voxA = lo half, voxB = hi half). v_pk_fma_f16 = 2x the f32 pipe rate.
// ROUND 23 (=R22 + compile fix): R20 structure + WAVE DE-PHASING.
// R19/R20/R21: VALUBusy pinned ~55% independent of TLP (4 vs 2 waves/SIMD),
// ILP (2 vs 4 chains), and coef load path (SMEM vs VMEM). Theory: waves are
// PHASE-LOCKED -- identical code, identical iteration length, launched
// together, no de-phasing mechanism -> per-iteration dependency bubbles
// (FMA->DPP hazard->cndmask chain) occur synchronously in all resident
// waves, so TLP/ILP cannot fill them. Fix: stagger wave start with
// s_sleep (constant-imm via switch) ~ 0/320/640/960 cyc + half-grid block
// term so bubbles anti-phase and interleave.
// Math is op-for-op identical to the passing R20 kernel.
// Rz-factorized RF (R11) with deferred relax, 3-phase live-cone (R14).
// Phases: A p<15 slot0 only; B 15..47 both slots; C 48..63 slot0 only.

#define NP2 64
#define ROR1  0x121   // row_ror:1 : dest lane i <- lane (i-1) & 15   (P: k <- k-1)
#define ROR15 0x12F   // row_ror:15: dest lane i <- lane (i+1) & 15   (M: k <- k+1)
#define RSHL1 0x101   // row_shl:1 : dest lane i <- lane i+1; lane15 <- 0 (bound_ctrl)

__device__ __forceinline__ unsigned h2u(__half2 x) {
    unsigned u; __builtin_memcpy(&u, &x, 4); return u;
}
__device__ __forceinline__ __half2 u2h(unsigned u) {
    __half2 h; __builtin_memcpy(&h, &u, 4); return h;
}
template<int CTRL>
__device__ __forceinline__ __half2 rroth(__half2 x) {
    return u2h((unsigned)__builtin_amdgcn_mov_dpp((int)h2u(x), CTRL, 0xF, 0xF, true));
}

// ---- pre-kernel: coefficient table [65][8] uints + pad in d_ws ----
// row p: [cd sd ca2 sa2 sa ca h 0], each uint = duplicated f16 pair.
// cd+i*sd = e^{i(phi_{p-1}-phi_p)} from unit vectors; phi_{-1}=0.
// uints 512..527 = zero pad (prefetch target).
__global__ void coef_kernel(const float* __restrict__ theta_re,
                            const float* __restrict__ theta_im,
                            unsigned* __restrict__ cw)
{
    const int t = threadIdx.x;
    if (t < NP2) {
        const float tre = theta_re[t], tim = theta_im[t];
        const float a2 = tre * tre + tim * tim;
        const float inva = __frsqrt_rn(a2);        // |theta| >= 0.1
        const float a = a2 * inva;
        const float c = tre * inva, s = tim * inva;   // cos/sin(phi_p)
        float cp = 1.f, sp = 0.f;                     // cos/sin(phi_{p-1})
        if (t > 0) {
            const float ure = theta_re[t - 1], uim = theta_im[t - 1];
            const float ia = __frsqrt_rn(ure * ure + uim * uim);
            cp = ure * ia; sp = uim * ia;
        }
        const float cd = cp * c + sp * s;          // cos(phi_{p-1}-phi_p)
        const float sd = sp * c - cp * s;          // sin(phi_{p-1}-phi_p)
        float sa, ca;
        __sincosf(a, &sa, &ca);
        const float ca2 = 0.5f + 0.5f * ca;        // cos^2(a/2)
        const float sa2 = 0.5f - 0.5f * ca;        // sin^2(a/2)
        unsigned* row = cw + t * 8;
        const float vals[8] = { cd, sd, ca2, sa2, sa, ca, 0.5f * sa, 0.f };
        for (int j = 0; j < 8; ++j) {
            const __half h = __float2half(vals[j]);
            __half2 hp = __halves2half2(h, h);
            unsigned u; __builtin_memcpy(&u, &hp, 4);
            row[j] = u;
        }
    } else if (t < NP2 + 16) {
        cw[NP2 * 8 + (t - NP2)] = 0u;              // zero pad rows (prefetch target)
    }
}

// one slot's matvec (both voxels via f16 halves); outputs unshifted nP/nM, updates Z
__device__ __forceinline__ void slot_mat(
    __half2 Pr, __half2 Pi, __half2 Mr, __half2 Mi, __half2& Zr, __half2& Zi,
    __half2 ec, __half2 es, __half2 esn,
    __half2 ca2, __half2 sa2, __half2 sa, __half2 ca, __half2 hh,
    __half2 pE1, __half2 rec,
    __half2& nPr, __half2& nPi, __half2& nMr, __half2& nMi)
{
    const __half2 hPr = __hfma2(ec, Pr, __hmul2(esn, Pi));
    const __half2 hPi = __hfma2(ec, Pi, __hmul2(es,  Pr));
    const __half2 hMr = __hfma2(ec, Mr, __hmul2(es,  Mi));
    const __half2 hMi = __hfma2(ec, Mi, __hmul2(esn, Mr));
    const __half2 ezr = __hfma2(pE1, Zr, rec);
    const __half2 ezi = __hmul2(pE1, Zi);
    const __half2 szr = __hmul2(sa, ezr);
    const __half2 szi = __hmul2(sa, ezi);
    const __half2 szrn = __hneg2(szr);
    const __half2 szin = __hneg2(szi);
    nPr = __hfma2(ca2, hPr, __hfma2(sa2, hMr, szi));
    nPi = __hfma2(ca2, hPi, __hfma2(sa2, hMi, szrn));
    nMr = __hfma2(sa2, hPr, __hfma2(ca2, hMr, szin));
    nMi = __hfma2(sa2, hPi, __hfma2(ca2, hMi, szr));
    Zr = __hfma2(hh, __hsub2(hPi, hMi), __hmul2(ca, ezr));
    Zi = __hfma2(hh, __hsub2(hMr, hPr), __hmul2(ca, ezi));
}

__global__ __launch_bounds__(256, 4) void epg_kernel(
    const float* __restrict__ TRp,
    const float* __restrict__ qmaps,
    const unsigned* __restrict__ cw,
    float* __restrict__ out, int V)
{
    const int t = threadIdx.x;
    const int sub = t & 15;           // lane within voxel group
    const int vloc = t >> 4;          // 0..15
    const int base = blockIdx.x * 64;
    const int vA = base + vloc;       // pair-a lo f16 half
    const int vB = vA + 16;           // pair-a hi f16 half
    const int vC = vA + 32;           // pair-b lo f16 half
    const int vD = vA + 48;           // pair-b hi f16 half

    __shared__ unsigned bufPrA[16][65], bufPiA[16][65];  // pair-a packed F~0, +1 pad
    __shared__ unsigned bufPrB[16][65], bufPiB[16][65];  // pair-b packed F~0

    const float tr = TRp[0];
    const float E1A = __expf(-tr / qmaps[V + vA]);
    const float E2A = __expf(-tr / qmaps[2 * V + vA]);
    const float E1B = __expf(-tr / qmaps[V + vB]);
    const float E2B = __expf(-tr / qmaps[2 * V + vB]);
    const float E1C = __expf(-tr / qmaps[V + vC]);
    const float E2C = __expf(-tr / qmaps[2 * V + vC]);
    const float E1D = __expf(-tr / qmaps[V + vD]);
    const float E2D = __expf(-tr / qmaps[2 * V + vD]);
    const bool s0 = (sub == 0);
    const bool s15 = (sub == 15);
    const __half2 pE1a = __floats2half2_rn(E1A, E1B);
    const __half2 pE2a = __floats2half2_rn(E2A, E2B);
    const __half2 pE1b = __floats2half2_rn(E1C, E1D);
    const __half2 pE2b = __floats2half2_rn(E2C, E2D);
    const __half2 zeroH = __floats2half2_rn(0.f, 0.f);
    const __half2 recHa = s0 ? __floats2half2_rn(1.f - E1A, 1.f - E1B) : zeroH;
    const __half2 recHb = s0 ? __floats2half2_rn(1.f - E1C, 1.f - E1D) : zeroH;

    // slot-packed state, 2 voxels per reg (f16 halves), two independent pairs
    __half2 Pr0a = zeroH, Pr1a = zeroH, Pi0a = zeroH, Pi1a = zeroH;
    __half2 Mr0a = zeroH, Mr1a = zeroH, Mi0a = zeroH, Mi1a = zeroH;
    __half2 Zr0a = s0 ? __floats2half2_rn(1.f, 1.f) : zeroH;   // E1*1+(1-E1)=1 exact
    __half2 Zr1a = zeroH, Zi0a = zeroH, Zi1a = zeroH;
    __half2 Pr0b = zeroH, Pr1b = zeroH, Pi0b = zeroH, Pi1b = zeroH;
    __half2 Mr0b = zeroH, Mr1b = zeroH, Mi0b = zeroH, Mi1b = zeroH;
    __half2 Zr0b = s0 ? __floats2half2_rn(1.f, 1.f) : zeroH;
    __half2 Zr1b = zeroH, Zi0b = zeroH, Zi1b = zeroH;

    // coefficient stream: plain uint4 loads, 1-iteration register prefetch
    const uint4* __restrict__ cwq = (const uint4*)cw;
    uint4 q0 = cwq[0], q1 = cwq[1];

    // ---- wave de-phasing stagger ----
    // Waves are phase-locked (identical code, launched together, no
    // de-phasing mechanism) -> per-iteration dep bubbles stall all waves
    // simultaneously. Stagger wave start (s_sleep imm = ~64*imm cycles) so
    // the bubbles anti-phase. Block parity term de-phases the co-resident
    // block pair. s_sleep needs a constant imm -> switch, executed once.
    {
        const int ph = (t >> 6) + 4 * ((blockIdx.x >> 8) & 1);  // 0..7
        switch (ph) {
            case 1: __builtin_amdgcn_s_sleep(5);  break;   // ~320 cyc
            case 2: __builtin_amdgcn_s_sleep(10); break;   // ~640
            case 3: __builtin_amdgcn_s_sleep(15); break;   // ~960
            case 4: __builtin_amdgcn_s_sleep(10); break;
            case 5: __builtin_amdgcn_s_sleep(15); break;
            case 6: __builtin_amdgcn_s_sleep(20); break;
            case 7: __builtin_amdgcn_s_sleep(25); break;
            default: break;
        }
    }

    __half2 nPr0a, nPi0a, nMr0a, nMi0a, nPr1a, nPi1a, nMr1a, nMi1a;
    __half2 nPr0b, nPi0b, nMr0b, nMi0b, nPr1b, nPi1b, nMr1b, nMi1b;

    // ---- phase A: p in [0,15), slot1 exactly zero -> slot0 only ----
#pragma unroll 1
    for (int p = 0; p < 15; ++p) {
        const int nb = 2 * (p + 1);
        const uint4 n0 = cwq[nb], n1 = cwq[nb + 1];
        const __half2 cd = u2h(q0.x), sd = u2h(q0.y);
        const __half2 ca2 = u2h(q0.z), sa2 = u2h(q0.w);
        const __half2 sa = u2h(q1.x), ca = u2h(q1.y), hh = u2h(q1.z);
        const __half2 eca = __hmul2(pE2a, cd);
        const __half2 esa = __hmul2(pE2a, sd);
        const __half2 esna = __hneg2(esa);
        const __half2 ecb = __hmul2(pE2b, cd);
        const __half2 esb = __hmul2(pE2b, sd);
        const __half2 esnb = __hneg2(esb);
        slot_mat(Pr0a, Pi0a, Mr0a, Mi0a, Zr0a, Zi0a, eca, esa, esna,
                 ca2, sa2, sa, ca, hh, pE1a, recHa, nPr0a, nPi0a, nMr0a, nMi0a);
        slot_mat(Pr0b, Pi0b, Mr0b, Mi0b, Zr0b, Zi0b, ecb, esb, esnb,
                 ca2, sa2, sa, ca, hh, pE1b, recHb, nPr0b, nPi0b, nMr0b, nMi0b);
        if (s0) {
            bufPrA[vloc][p] = h2u(nPr0a); bufPiA[vloc][p] = h2u(nPi0a);
            bufPrB[vloc][p] = h2u(nPr0b); bufPiB[vloc][p] = h2u(nPi0b);
        }
        const __half2 rPra = rroth<ROR1>(nPr0a);
        const __half2 rPia = rroth<ROR1>(nPi0a);
        const __half2 rMra = rroth<RSHL1>(nMr0a);  // lane i <- i+1; lane15 <- 0
        const __half2 rMia = rroth<RSHL1>(nMi0a);
        const __half2 rPrb = rroth<ROR1>(nPr0b);
        const __half2 rPib = rroth<ROR1>(nPi0b);
        const __half2 rMrb = rroth<RSHL1>(nMr0b);
        const __half2 rMib = rroth<RSHL1>(nMi0b);
        Pr0a = s0 ? rMra : rPra;                   // level0 <- conj(M'_1)
        Pi0a = s0 ? __hneg2(rMia) : rPia;
        Mr0a = rMra;                               // lane15: 0 (exact: M'_16 = 0)
        Mi0a = rMia;
        Pr0b = s0 ? rMrb : rPrb;
        Pi0b = s0 ? __hneg2(rMib) : rPib;
        Mr0b = rMrb;
        Mi0b = rMib;
        q0 = n0; q1 = n1;
    }

    // ---- phase B: p in [15,48), both slots live ----
#pragma unroll 1
    for (int p = 15; p < 48; ++p) {
        const int nb = 2 * (p + 1);
        const uint4 n0 = cwq[nb], n1 = cwq[nb + 1];
        const __half2 cd = u2h(q0.x), sd = u2h(q0.y);
        const __half2 ca2 = u2h(q0.z), sa2 = u2h(q0.w);
        const __half2 sa = u2h(q1.x), ca = u2h(q1.y), hh = u2h(q1.z);
        const __half2 eca = __hmul2(pE2a, cd);
        const __half2 esa = __hmul2(pE2a, sd);
        const __half2 esna = __hneg2(esa);
        const __half2 ecb = __hmul2(pE2b, cd);
        const __half2 esb = __hmul2(pE2b, sd);
        const __half2 esnb = __hneg2(esb);
        slot_mat(Pr0a, Pi0a, Mr0a, Mi0a, Zr0a, Zi0a, eca, esa, esna,
                 ca2, sa2, sa, ca, hh, pE1a, recHa, nPr0a, nPi0a, nMr0a, nMi0a);
        slot_mat(Pr1a, Pi1a, Mr1a, Mi1a, Zr1a, Zi1a, eca, esa, esna,
                 ca2, sa2, sa, ca, hh, pE1a, zeroH, nPr1a, nPi1a, nMr1a, nMi1a);
        slot_mat(Pr0b, Pi0b, Mr0b, Mi0b, Zr0b, Zi0b, ecb, esb, esnb,
                 ca2, sa2, sa, ca, hh, pE1b, recHb, nPr0b, nPi0b, nMr0b, nMi0b);
        slot_mat(Pr1b, Pi1b, Mr1b, Mi1b, Zr1b, Zi1b, ecb, esb, esnb,
                 ca2, sa2, sa, ca, hh, pE1b, zeroH, nPr1b, nPi1b, nMr1b, nMi1b);
        if (s0) {
            bufPrA[vloc][p] = h2u(nPr0a); bufPiA[vloc][p] = h2u(nPi0a);
            bufPrB[vloc][p] = h2u(nPr0b); bufPiB[vloc][p] = h2u(nPi0b);
        }
        const __half2 rPr0a = rroth<ROR1>(nPr0a),  rPr1a = rroth<ROR1>(nPr1a);
        const __half2 rPi0a = rroth<ROR1>(nPi0a),  rPi1a = rroth<ROR1>(nPi1a);
        const __half2 rMr0a = rroth<ROR15>(nMr0a), rMr1a = rroth<ROR15>(nMr1a);
        const __half2 rMi0a = rroth<ROR15>(nMi0a), rMi1a = rroth<ROR15>(nMi1a);
        const __half2 rPr0b = rroth<ROR1>(nPr0b),  rPr1b = rroth<ROR1>(nPr1b);
        const __half2 rPi0b = rroth<ROR1>(nPi0b),  rPi1b = rroth<ROR1>(nPi1b);
        const __half2 rMr0b = rroth<ROR15>(nMr0b), rMr1b = rroth<ROR15>(nMr1b);
        const __half2 rMi0b = rroth<ROR15>(nMi0b), rMi1b = rroth<ROR15>(nMi1b);
        Pr1a = s0 ? rPr0a : rPr1a;                 // level16 <- P'_15
        Pi1a = s0 ? rPi0a : rPi1a;
        Pr0a = s0 ? rMr0a : rPr0a;                 // level0 <- conj(M'_1)
        Pi0a = s0 ? __hneg2(rMi0a) : rPi0a;
        Mr0a = s15 ? rMr1a : rMr0a;                // level15 <- M'_16
        Mi0a = s15 ? rMi1a : rMi0a;
        Mr1a = s15 ? zeroH : rMr1a;                // level31 <- M'_32 = 0 exactly
        Mi1a = s15 ? zeroH : rMi1a;
        Pr1b = s0 ? rPr0b : rPr1b;
        Pi1b = s0 ? rPi0b : rPi1b;
        Pr0b = s0 ? rMr0b : rPr0b;
        Pi0b = s0 ? __hneg2(rMi0b) : rPi0b;
        Mr0b = s15 ? rMr1b : rMr0b;
        Mi0b = s15 ? rMi1b : rMi0b;
        Mr1b = s15 ? zeroH : rMr1b;
        Mi1b = s15 ? zeroH : rMi1b;
        q0 = n0; q1 = n1;
    }

    // ---- phase C: p in [48,64), slot1 in the dead cone -> slot0 only ----
#pragma unroll 1
    for (int p = 48; p < NP2; ++p) {
        const int nb = 2 * (p + 1);
        const uint4 n0 = cwq[nb], n1 = cwq[nb + 1];
        const __half2 cd = u2h(q0.x), sd = u2h(q0.y);
        const __half2 ca2 = u2h(q0.z), sa2 = u2h(q0.w);
        const __half2 sa = u2h(q1.x), ca = u2h(q1.y), hh = u2h(q1.z);
        const __half2 eca = __hmul2(pE2a, cd);
        const __half2 esa = __hmul2(pE2a, sd);
        const __half2 esna = __hneg2(esa);
        const __half2 ecb = __hmul2(pE2b, cd);
        const __half2 esb = __hmul2(pE2b, sd);
        const __half2 esnb = __hneg2(esb);
        slot_mat(Pr0a, Pi0a, Mr0a, Mi0a, Zr0a, Zi0a, eca, esa, esna,
                 ca2, sa2, sa, ca, hh, pE1a, recHa, nPr0a, nPi0a, nMr0a, nMi0a);
        slot_mat(Pr0b, Pi0b, Mr0b, Mi0b, Zr0b, Zi0b, ecb, esb, esnb,
                 ca2, sa2, sa, ca, hh, pE1b, recHb, nPr0b, nPi0b, nMr0b, nMi0b);
        if (s0) {
            bufPrA[vloc][p] = h2u(nPr0a); bufPiA[vloc][p] = h2u(nPi0a);
            bufPrB[vloc][p] = h2u(nPr0b); bufPiB[vloc][p] = h2u(nPi0b);
        }
        const __half2 rPra = rroth<ROR1>(nPr0a);
        const __half2 rPia = rroth<ROR1>(nPi0a);
        const __half2 rMra = rroth<RSHL1>(nMr0a);  // lane15's junk: dead cone
        const __half2 rMia = rroth<RSHL1>(nMi0a);
        const __half2 rPrb = rroth<ROR1>(nPr0b);
        const __half2 rPib = rroth<ROR1>(nPi0b);
        const __half2 rMrb = rroth<RSHL1>(nMr0b);
        const __half2 rMib = rroth<RSHL1>(nMi0b);
        Pr0a = s0 ? rMra : rPra;
        Pi0a = s0 ? __hneg2(rMia) : rPia;
        Mr0a = rMra;
        Mi0a = rMia;
        Pr0b = s0 ? rMrb : rPrb;
        Pi0b = s0 ? __hneg2(rMib) : rPib;
        Mr0b = rMrb;
        Mi0b = rMib;
        q0 = n0; q1 = n1;
    }

    // ---- epilogue: unpack f16 halves, magnitude * PD (f32), coalesced stores ----
    __syncthreads();
    float4* out4 = (float4*)out;
#pragma unroll
    for (int i = 0; i < 4; ++i) {
        const int q = i * 256 + t;
        const int r = q >> 4;              // output voxel row 0..63
        const int c = (q & 15) * 4;        // pulse col
        const int row = r & 15;            // state row
        const bool hi = (r >> 4) & 1;      // which f16 half
        const bool pb = (r >> 5) & 1;      // which pair buffer
        const float PDr = qmaps[base + r];
        float4 val;
        float* vp = &val.x;
#pragma unroll
        for (int j = 0; j < 4; ++j) {
            const unsigned ur = pb ? bufPrB[row][c + j] : bufPrA[row][c + j];
            const unsigned ui = pb ? bufPiB[row][c + j] : bufPiA[row][c + j];
            const __half2 hr = u2h(ur);
            const __half2 hii = u2h(ui);
            const float pr = hi ? __high2float(hr) : __low2float(hr);
            const float pi = hi ? __high2float(hii) : __low2float(hii);
            vp[j] = sqrtf(pr * pr + pi * pi) * PDr;
        }
        out4[blockIdx.x * 1024 + q] = val;
    }
}

extern "C" void kernel_launch(void* const* d_in, const int* in_sizes, int n_in,
                              void* d_out, int out_size, void* d_ws, size_t ws_size,
                              hipStream_t stream) {
    const float* theta_re = (const float*)d_in[0];
    const float* theta_im = (const float*)d_in[1];
    const float* TRp      = (const float*)d_in[2];
    const float* qmaps    = (const float*)d_in[3];
    float* out = (float*)d_out;
    unsigned* cw = (unsigned*)d_ws;            // [66][8] uints = 2112 B (tail = pad)
    const int V = in_sizes[3] / 3;             // qmaps is [3, V, 1]
    coef_kernel<<<dim3(1), dim3(128), 0, stream>>>(theta_re, theta_im, cw);
    epg_kernel<<<dim3(V / 64), dim3(256), 0, stream>>>(TRp, qmaps, cw, out, V);
}

// Round 5
// 94.034 us; speedup vs baseline: 1.0511x; 1.0213x over previous
//
#include <hip/hip_runtime.h>
#include <hip/hip_fp16.h>
#include <math.h>

// EPG GRE F0, NP2=64 pulses, V voxels.
// 16 lanes per voxel-pair: lane sub (0..15) holds levels k0=sub (slot0),
// k1=16+sub (slot1) for TWO voxels packed in the f16 halves of each 32-bit reg
// (voxA = lo half, voxB = hi half). v_pk_fma_f16 = 2x the f32 pipe rate.
// ROUND 24: R20 structure (fastest verified, 40.4us) + FUSED coef table.
// Evidence through R23: VALUBusy pinned ~55% under TLP x2, ILP x2, SMEM->VMEM
// coef path, and wave de-phasing -> the kernel is VALU-ISSUE-RATE-BOUND
// (m07 microbench: even a pure FMA stream sustains only ~66% busy on this
// chip; our SALU/DS-mixed stream at 55% is ~0.83x of that ceiling), and
// time tracks instruction count. Remaining movable overhead is the separate
// coef_kernel dispatch + inter-kernel bubble (~4-6us of the fixed ~54us):
// fuse it. Each block computes the 65x8 coef table into LDS once (threads
// t<64, one barrier); the loop reads rows via broadcast ds_read_b128 with
// the same 1-iteration register prefetch. Math is op-for-op identical to
// the passing R20 kernel.
// Rz-factorized RF (R11) with deferred relax, 3-phase live-cone (R14).
// Phases: A p<15 slot0 only; B 15..47 both slots; C 48..63 slot0 only.

#define NP2 64
#define ROR1  0x121   // row_ror:1 : dest lane i <- lane (i-1) & 15   (P: k <- k-1)
#define ROR15 0x12F   // row_ror:15: dest lane i <- lane (i+1) & 15   (M: k <- k+1)
#define RSHL1 0x101   // row_shl:1 : dest lane i <- lane i+1; lane15 <- 0 (bound_ctrl)

__device__ __forceinline__ unsigned h2u(__half2 x) {
    unsigned u; __builtin_memcpy(&u, &x, 4); return u;
}
__device__ __forceinline__ __half2 u2h(unsigned u) {
    __half2 h; __builtin_memcpy(&h, &u, 4); return h;
}
template<int CTRL>
__device__ __forceinline__ __half2 rroth(__half2 x) {
    return u2h((unsigned)__builtin_amdgcn_mov_dpp((int)h2u(x), CTRL, 0xF, 0xF, true));
}

// one slot's matvec (both voxels via f16 halves); outputs unshifted nP/nM, updates Z
__device__ __forceinline__ void slot_mat(
    __half2 Pr, __half2 Pi, __half2 Mr, __half2 Mi, __half2& Zr, __half2& Zi,
    __half2 ec, __half2 es, __half2 esn,
    __half2 ca2, __half2 sa2, __half2 sa, __half2 ca, __half2 hh,
    __half2 pE1, __half2 rec,
    __half2& nPr, __half2& nPi, __half2& nMr, __half2& nMi)
{
    const __half2 hPr = __hfma2(ec, Pr, __hmul2(esn, Pi));
    const __half2 hPi = __hfma2(ec, Pi, __hmul2(es,  Pr));
    const __half2 hMr = __hfma2(ec, Mr, __hmul2(es,  Mi));
    const __half2 hMi = __hfma2(ec, Mi, __hmul2(esn, Mr));
    const __half2 ezr = __hfma2(pE1, Zr, rec);
    const __half2 ezi = __hmul2(pE1, Zi);
    const __half2 szr = __hmul2(sa, ezr);
    const __half2 szi = __hmul2(sa, ezi);
    const __half2 szrn = __hneg2(szr);
    const __half2 szin = __hneg2(szi);
    nPr = __hfma2(ca2, hPr, __hfma2(sa2, hMr, szi));
    nPi = __hfma2(ca2, hPi, __hfma2(sa2, hMi, szrn));
    nMr = __hfma2(sa2, hPr, __hfma2(ca2, hMr, szin));
    nMi = __hfma2(sa2, hPi, __hfma2(ca2, hMi, szr));
    Zr = __hfma2(hh, __hsub2(hPi, hMi), __hmul2(ca, ezr));
    Zi = __hfma2(hh, __hsub2(hMr, hPr), __hmul2(ca, ezi));
}

__global__ __launch_bounds__(256, 4) void epg_kernel(
    const float* __restrict__ theta_re,
    const float* __restrict__ theta_im,
    const float* __restrict__ TRp,
    const float* __restrict__ qmaps,
    float* __restrict__ out, int V)
{
    const int t = threadIdx.x;
    const int sub = t & 15;           // lane within voxel group
    const int vloc = t >> 4;          // 0..15
    const int base = blockIdx.x * 64;
    const int vA = base + vloc;       // pair-a lo f16 half
    const int vB = vA + 16;           // pair-a hi f16 half
    const int vC = vA + 32;           // pair-b lo f16 half
    const int vD = vA + 48;           // pair-b hi f16 half

    __shared__ unsigned bufPrA[16][65], bufPiA[16][65];  // pair-a packed F~0, +1 pad
    __shared__ unsigned bufPrB[16][65], bufPiB[16][65];  // pair-b packed F~0
    // fused coef table [66][8] uints: row p = [cd sd ca2 sa2 sa ca h 0],
    // each uint = duplicated f16 pair; rows 64,65 = zero pad (prefetch target)
    __shared__ __align__(16) unsigned cwl[528];

    // ---- per-block coefficient table (was a separate kernel pre-R24) ----
    if (t < NP2) {
        const float tre = theta_re[t], tim = theta_im[t];
        const float a2 = tre * tre + tim * tim;
        const float inva = __frsqrt_rn(a2);        // |theta| >= 0.1
        const float a = a2 * inva;
        const float c = tre * inva, s = tim * inva;   // cos/sin(phi_p)
        float cp = 1.f, sp = 0.f;                     // cos/sin(phi_{p-1})
        if (t > 0) {
            const float ure = theta_re[t - 1], uim = theta_im[t - 1];
            const float ia = __frsqrt_rn(ure * ure + uim * uim);
            cp = ure * ia; sp = uim * ia;
        }
        const float cd = cp * c + sp * s;          // cos(phi_{p-1}-phi_p)
        const float sd = sp * c - cp * s;          // sin(phi_{p-1}-phi_p)
        float sa, ca;
        __sincosf(a, &sa, &ca);
        const float ca2 = 0.5f + 0.5f * ca;        // cos^2(a/2)
        const float sa2 = 0.5f - 0.5f * ca;        // sin^2(a/2)
        unsigned* row = cwl + t * 8;
        const float vals[8] = { cd, sd, ca2, sa2, sa, ca, 0.5f * sa, 0.f };
#pragma unroll
        for (int j = 0; j < 8; ++j) {
            const __half h = __float2half(vals[j]);
            __half2 hp = __halves2half2(h, h);
            unsigned u; __builtin_memcpy(&u, &hp, 4);
            row[j] = u;
        }
    } else if (t < NP2 + 16) {
        cwl[NP2 * 8 + (t - NP2)] = 0u;             // zero pad rows 64,65
    }

    const float tr = TRp[0];
    const float E1A = __expf(-tr / qmaps[V + vA]);
    const float E2A = __expf(-tr / qmaps[2 * V + vA]);
    const float E1B = __expf(-tr / qmaps[V + vB]);
    const float E2B = __expf(-tr / qmaps[2 * V + vB]);
    const float E1C = __expf(-tr / qmaps[V + vC]);
    const float E2C = __expf(-tr / qmaps[2 * V + vC]);
    const float E1D = __expf(-tr / qmaps[V + vD]);
    const float E2D = __expf(-tr / qmaps[2 * V + vD]);
    const bool s0 = (sub == 0);
    const bool s15 = (sub == 15);
    const __half2 pE1a = __floats2half2_rn(E1A, E1B);
    const __half2 pE2a = __floats2half2_rn(E2A, E2B);
    const __half2 pE1b = __floats2half2_rn(E1C, E1D);
    const __half2 pE2b = __floats2half2_rn(E2C, E2D);
    const __half2 zeroH = __floats2half2_rn(0.f, 0.f);
    const __half2 recHa = s0 ? __floats2half2_rn(1.f - E1A, 1.f - E1B) : zeroH;
    const __half2 recHb = s0 ? __floats2half2_rn(1.f - E1C, 1.f - E1D) : zeroH;

    // slot-packed state, 2 voxels per reg (f16 halves), two independent pairs
    __half2 Pr0a = zeroH, Pr1a = zeroH, Pi0a = zeroH, Pi1a = zeroH;
    __half2 Mr0a = zeroH, Mr1a = zeroH, Mi0a = zeroH, Mi1a = zeroH;
    __half2 Zr0a = s0 ? __floats2half2_rn(1.f, 1.f) : zeroH;   // E1*1+(1-E1)=1 exact
    __half2 Zr1a = zeroH, Zi0a = zeroH, Zi1a = zeroH;
    __half2 Pr0b = zeroH, Pr1b = zeroH, Pi0b = zeroH, Pi1b = zeroH;
    __half2 Mr0b = zeroH, Mr1b = zeroH, Mi0b = zeroH, Mi1b = zeroH;
    __half2 Zr0b = s0 ? __floats2half2_rn(1.f, 1.f) : zeroH;
    __half2 Zr1b = zeroH, Zi0b = zeroH, Zi1b = zeroH;

    __syncthreads();                               // coef table ready

    // coefficient stream: broadcast ds_read_b128 pairs, 1-iteration prefetch
    const uint4* __restrict__ cwq = (const uint4*)cwl;
    uint4 q0 = cwq[0], q1 = cwq[1];

    __half2 nPr0a, nPi0a, nMr0a, nMi0a, nPr1a, nPi1a, nMr1a, nMi1a;
    __half2 nPr0b, nPi0b, nMr0b, nMi0b, nPr1b, nPi1b, nMr1b, nMi1b;

    // ---- phase A: p in [0,15), slot1 exactly zero -> slot0 only ----
#pragma unroll 1
    for (int p = 0; p < 15; ++p) {
        const int nb = 2 * (p + 1);
        const uint4 n0 = cwq[nb], n1 = cwq[nb + 1];
        const __half2 cd = u2h(q0.x), sd = u2h(q0.y);
        const __half2 ca2 = u2h(q0.z), sa2 = u2h(q0.w);
        const __half2 sa = u2h(q1.x), ca = u2h(q1.y), hh = u2h(q1.z);
        const __half2 eca = __hmul2(pE2a, cd);
        const __half2 esa = __hmul2(pE2a, sd);
        const __half2 esna = __hneg2(esa);
        const __half2 ecb = __hmul2(pE2b, cd);
        const __half2 esb = __hmul2(pE2b, sd);
        const __half2 esnb = __hneg2(esb);
        slot_mat(Pr0a, Pi0a, Mr0a, Mi0a, Zr0a, Zi0a, eca, esa, esna,
                 ca2, sa2, sa, ca, hh, pE1a, recHa, nPr0a, nPi0a, nMr0a, nMi0a);
        slot_mat(Pr0b, Pi0b, Mr0b, Mi0b, Zr0b, Zi0b, ecb, esb, esnb,
                 ca2, sa2, sa, ca, hh, pE1b, recHb, nPr0b, nPi0b, nMr0b, nMi0b);
        if (s0) {
            bufPrA[vloc][p] = h2u(nPr0a); bufPiA[vloc][p] = h2u(nPi0a);
            bufPrB[vloc][p] = h2u(nPr0b); bufPiB[vloc][p] = h2u(nPi0b);
        }
        const __half2 rPra = rroth<ROR1>(nPr0a);
        const __half2 rPia = rroth<ROR1>(nPi0a);
        const __half2 rMra = rroth<RSHL1>(nMr0a);  // lane i <- i+1; lane15 <- 0
        const __half2 rMia = rroth<RSHL1>(nMi0a);
        const __half2 rPrb = rroth<ROR1>(nPr0b);
        const __half2 rPib = rroth<ROR1>(nPi0b);
        const __half2 rMrb = rroth<RSHL1>(nMr0b);
        const __half2 rMib = rroth<RSHL1>(nMi0b);
        Pr0a = s0 ? rMra : rPra;                   // level0 <- conj(M'_1)
        Pi0a = s0 ? __hneg2(rMia) : rPia;
        Mr0a = rMra;                               // lane15: 0 (exact: M'_16 = 0)
        Mi0a = rMia;
        Pr0b = s0 ? rMrb : rPrb;
        Pi0b = s0 ? __hneg2(rMib) : rPib;
        Mr0b = rMrb;
        Mi0b = rMib;
        q0 = n0; q1 = n1;
    }

    // ---- phase B: p in [15,48), both slots live ----
#pragma unroll 1
    for (int p = 15; p < 48; ++p) {
        const int nb = 2 * (p + 1);
        const uint4 n0 = cwq[nb], n1 = cwq[nb + 1];
        const __half2 cd = u2h(q0.x), sd = u2h(q0.y);
        const __half2 ca2 = u2h(q0.z), sa2 = u2h(q0.w);
        const __half2 sa = u2h(q1.x), ca = u2h(q1.y), hh = u2h(q1.z);
        const __half2 eca = __hmul2(pE2a, cd);
        const __half2 esa = __hmul2(pE2a, sd);
        const __half2 esna = __hneg2(esa);
        const __half2 ecb = __hmul2(pE2b, cd);
        const __half2 esb = __hmul2(pE2b, sd);
        const __half2 esnb = __hneg2(esb);
        slot_mat(Pr0a, Pi0a, Mr0a, Mi0a, Zr0a, Zi0a, eca, esa, esna,
                 ca2, sa2, sa, ca, hh, pE1a, recHa, nPr0a, nPi0a, nMr0a, nMi0a);
        slot_mat(Pr1a, Pi1a, Mr1a, Mi1a, Zr1a, Zi1a, eca, esa, esna,
                 ca2, sa2, sa, ca, hh, pE1a, zeroH, nPr1a, nPi1a, nMr1a, nMi1a);
        slot_mat(Pr0b, Pi0b, Mr0b, Mi0b, Zr0b, Zi0b, ecb, esb, esnb,
                 ca2, sa2, sa, ca, hh, pE1b, recHb, nPr0b, nPi0b, nMr0b, nMi0b);
        slot_mat(Pr1b, Pi1b, Mr1b, Mi1b, Zr1b, Zi1b, ecb, esb, esnb,
                 ca2, sa2, sa, ca, hh, pE1b, zeroH, nPr1b, nPi1b, nMr1b, nMi1b);
        if (s0) {
            bufPrA[vloc][p] = h2u(nPr0a); bufPiA[vloc][p] = h2u(nPi0a);
            bufPrB[vloc][p] = h2u(nPr0b); bufPiB[vloc][p] = h2u(nPi0b);
        }
        const __half2 rPr0a = rroth<ROR1>(nPr0a),  rPr1a = rroth<ROR1>(nPr1a);
        const __half2 rPi0a = rroth<ROR1>(nPi0a),  rPi1a = rroth<ROR1>(nPi1a);
        const __half2 rMr0a = rroth<ROR15>(nMr0a), rMr1a = rroth<ROR15>(nMr1a);
        const __half2 rMi0a = rroth<ROR15>(nMi0a), rMi1a = rroth<ROR15>(nMi1a);
        const __half2 rPr0b = rroth<ROR1>(nPr0b),  rPr1b = rroth<ROR1>(nPr1b);
        const __half2 rPi0b = rroth<ROR1>(nPi0b),  rPi1b = rroth<ROR1>(nPi1b);
        const __half2 rMr0b = rroth<ROR15>(nMr0b), rMr1b = rroth<ROR15>(nMr1b);
        const __half2 rMi0b = rroth<ROR15>(nMi0b), rMi1b = rroth<ROR15>(nMi1b);
        Pr1a = s0 ? rPr0a : rPr1a;                 // level16 <- P'_15
        Pi1a = s0 ? rPi0a : rPi1a;
        Pr0a = s0 ? rMr0a : rPr0a;                 // level0 <- conj(M'_1)
        Pi0a = s0 ? __hneg2(rMi0a) : rPi0a;
        Mr0a = s15 ? rMr1a : rMr0a;                // level15 <- M'_16
        Mi0a = s15 ? rMi1a : rMi0a;
        Mr1a = s15 ? zeroH : rMr1a;                // level31 <- M'_32 = 0 exactly
        Mi1a = s15 ? zeroH : rMi1a;
        Pr1b = s0 ? rPr0b : rPr1b;
        Pi1b = s0 ? rPi0b : rPi1b;
        Pr0b = s0 ? rMr0b : rPr0b;
        Pi0b = s0 ? __hneg2(rMi0b) : rPi0b;
        Mr0b = s15 ? rMr1b : rMr0b;
        Mi0b = s15 ? rMi1b : rMi0b;
        Mr1b = s15 ? zeroH : rMr1b;
        Mi1b = s15 ? zeroH : rMi1b;
        q0 = n0; q1 = n1;
    }

    // ---- phase C: p in [48,64), slot1 in the dead cone -> slot0 only ----
#pragma unroll 1
    for (int p = 48; p < NP2; ++p) {
        const int nb = 2 * (p + 1);
        const uint4 n0 = cwq[nb], n1 = cwq[nb + 1];
        const __half2 cd = u2h(q0.x), sd = u2h(q0.y);
        const __half2 ca2 = u2h(q0.z), sa2 = u2h(q0.w);
        const __half2 sa = u2h(q1.x), ca = u2h(q1.y), hh = u2h(q1.z);
        const __half2 eca = __hmul2(pE2a, cd);
        const __half2 esa = __hmul2(pE2a, sd);
        const __half2 esna = __hneg2(esa);
        const __half2 ecb = __hmul2(pE2b, cd);
        const __half2 esb = __hmul2(pE2b, sd);
        const __half2 esnb = __hneg2(esb);
        slot_mat(Pr0a, Pi0a, Mr0a, Mi0a, Zr0a, Zi0a, eca, esa, esna,
                 ca2, sa2, sa, ca, hh, pE1a, recHa, nPr0a, nPi0a, nMr0a, nMi0a);
        slot_mat(Pr0b, Pi0b, Mr0b, Mi0b, Zr0b, Zi0b, ecb, esb, esnb,
                 ca2, sa2, sa, ca, hh, pE1b, recHb, nPr0b, nPi0b, nMr0b, nMi0b);
        if (s0) {
            bufPrA[vloc][p] = h2u(nPr0a); bufPiA[vloc][p] = h2u(nPi0a);
            bufPrB[vloc][p] = h2u(nPr0b); bufPiB[vloc][p] = h2u(nPi0b);
        }
        const __half2 rPra = rroth<ROR1>(nPr0a);
        const __half2 rPia = rroth<ROR1>(nPi0a);
        const __half2 rMra = rroth<RSHL1>(nMr0a);  // lane15's junk: dead cone
        const __half2 rMia = rroth<RSHL1>(nMi0a);
        const __half2 rPrb = rroth<ROR1>(nPr0b);
        const __half2 rPib = rroth<ROR1>(nPi0b);
        const __half2 rMrb = rroth<RSHL1>(nMr0b);
        const __half2 rMib = rroth<RSHL1>(nMi0b);
        Pr0a = s0 ? rMra : rPra;
        Pi0a = s0 ? __hneg2(rMia) : rPia;
        Mr0a = rMra;
        Mi0a = rMia;
        Pr0b = s0 ? rMrb : rPrb;
        Pi0b = s0 ? __hneg2(rMib) : rPib;
        Mr0b = rMrb;
        Mi0b = rMib;
        q0 = n0; q1 = n1;
    }

    // ---- epilogue: unpack f16 halves, magnitude * PD (f32), coalesced stores ----
    __syncthreads();
    float4* out4 = (float4*)out;
#pragma unroll
    for (int i = 0; i < 4; ++i) {
        const int q = i * 256 + t;
        const int r = q >> 4;              // output voxel row 0..63
        const int c = (q & 15) * 4;        // pulse col
        const int row = r & 15;            // state row
        const bool hi = (r >> 4) & 1;      // which f16 half
        const bool pb = (r >> 5) & 1;      // which pair buffer
        const float PDr = qmaps[base + r];
        float4 val;
        float* vp = &val.x;
#pragma unroll
        for (int j = 0; j < 4; ++j) {
            const unsigned ur = pb ? bufPrB[row][c + j] : bufPrA[row][c + j];
            const unsigned ui = pb ? bufPiB[row][c + j] : bufPiA[row][c + j];
            const __half2 hr = u2h(ur);
            const __half2 hii = u2h(ui);
            const float pr = hi ? __high2float(hr) : __low2float(hr);
            const float pi = hi ? __high2float(hii) : __low2float(hii);
            vp[j] = sqrtf(pr * pr + pi * pi) * PDr;
        }
        out4[blockIdx.x * 1024 + q] = val;
    }
}

extern "C" void kernel_launch(void* const* d_in, const int* in_sizes, int n_in,
                              void* d_out, int out_size, void* d_ws, size_t ws_size,
                              hipStream_t stream) {
    const float* theta_re = (const float*)d_in[0];
    const float* theta_im = (const float*)d_in[1];
    const float* TRp      = (const float*)d_in[2];
    const float* qmaps    = (const float*)d_in[3];
    float* out = (float*)d_out;
    const int V = in_sizes[3] / 3;             // qmaps is [3, V, 1]
    (void)d_ws; (void)ws_size;
    epg_kernel<<<dim3(V / 64), dim3(256), 0, stream>>>(
        theta_re, theta_im, TRp, qmaps, out, V);
}

// Round 6
// 93.484 us; speedup vs baseline: 1.0573x; 1.0059x over previous
//
#include <hip/hip_runtime.h>
#include <hip/hip_fp16.h>
#include <math.h>

// EPG GRE F0, NP2=64 pulses, V voxels.
// 16 lanes per voxel-pair: lane sub (0..15) holds levels k0=sub (slot0),
// k1=16+sub (slot1) for TWO voxels packed in the f16 halves of each 32-bit reg
// (voxA = lo half, voxB = hi half). v_pk_fma_f16 = 2x the f32 pipe rate.
// ROUND 25: R24 (fused coef, 41.3us epg) + UNROLL 2.
// Evidence through R24: VALU-issue-rate-bound; VALUBusy 58.6% vs ~66%
// practical stream ceiling (m07). The residual gap is per-iteration
// non-VALU issue slots: loop SALU + s_cbranch + ds_read waits. The loops
// were pinned at unroll 1 (old I$ concern -- obsolete: phase B x2 = ~9KB
// << 32KB I$). Unroll 2 amortizes loop overhead and lets the scheduler
// overlap iteration p+1's coef prep with iteration p's dependent tail.
// Math is op-for-op identical to the passing R24 kernel.
// Rz-factorized RF (R11) with deferred relax, 3-phase live-cone (R14).
// Phases: A p<15 slot0 only; B 15..47 both slots; C 48..63 slot0 only.

#define NP2 64
#define ROR1  0x121   // row_ror:1 : dest lane i <- lane (i-1) & 15   (P: k <- k-1)
#define ROR15 0x12F   // row_ror:15: dest lane i <- lane (i+1) & 15   (M: k <- k+1)
#define RSHL1 0x101   // row_shl:1 : dest lane i <- lane i+1; lane15 <- 0 (bound_ctrl)

__device__ __forceinline__ unsigned h2u(__half2 x) {
    unsigned u; __builtin_memcpy(&u, &x, 4); return u;
}
__device__ __forceinline__ __half2 u2h(unsigned u) {
    __half2 h; __builtin_memcpy(&h, &u, 4); return h;
}
template<int CTRL>
__device__ __forceinline__ __half2 rroth(__half2 x) {
    return u2h((unsigned)__builtin_amdgcn_mov_dpp((int)h2u(x), CTRL, 0xF, 0xF, true));
}

// one slot's matvec (both voxels via f16 halves); outputs unshifted nP/nM, updates Z
__device__ __forceinline__ void slot_mat(
    __half2 Pr, __half2 Pi, __half2 Mr, __half2 Mi, __half2& Zr, __half2& Zi,
    __half2 ec, __half2 es, __half2 esn,
    __half2 ca2, __half2 sa2, __half2 sa, __half2 ca, __half2 hh,
    __half2 pE1, __half2 rec,
    __half2& nPr, __half2& nPi, __half2& nMr, __half2& nMi)
{
    const __half2 hPr = __hfma2(ec, Pr, __hmul2(esn, Pi));
    const __half2 hPi = __hfma2(ec, Pi, __hmul2(es,  Pr));
    const __half2 hMr = __hfma2(ec, Mr, __hmul2(es,  Mi));
    const __half2 hMi = __hfma2(ec, Mi, __hmul2(esn, Mr));
    const __half2 ezr = __hfma2(pE1, Zr, rec);
    const __half2 ezi = __hmul2(pE1, Zi);
    const __half2 szr = __hmul2(sa, ezr);
    const __half2 szi = __hmul2(sa, ezi);
    const __half2 szrn = __hneg2(szr);
    const __half2 szin = __hneg2(szi);
    nPr = __hfma2(ca2, hPr, __hfma2(sa2, hMr, szi));
    nPi = __hfma2(ca2, hPi, __hfma2(sa2, hMi, szrn));
    nMr = __hfma2(sa2, hPr, __hfma2(ca2, hMr, szin));
    nMi = __hfma2(sa2, hPi, __hfma2(ca2, hMi, szr));
    Zr = __hfma2(hh, __hsub2(hPi, hMi), __hmul2(ca, ezr));
    Zi = __hfma2(hh, __hsub2(hMr, hPr), __hmul2(ca, ezi));
}

__global__ __launch_bounds__(256, 4) void epg_kernel(
    const float* __restrict__ theta_re,
    const float* __restrict__ theta_im,
    const float* __restrict__ TRp,
    const float* __restrict__ qmaps,
    float* __restrict__ out, int V)
{
    const int t = threadIdx.x;
    const int sub = t & 15;           // lane within voxel group
    const int vloc = t >> 4;          // 0..15
    const int base = blockIdx.x * 64;
    const int vA = base + vloc;       // pair-a lo f16 half
    const int vB = vA + 16;           // pair-a hi f16 half
    const int vC = vA + 32;           // pair-b lo f16 half
    const int vD = vA + 48;           // pair-b hi f16 half

    __shared__ unsigned bufPrA[16][65], bufPiA[16][65];  // pair-a packed F~0, +1 pad
    __shared__ unsigned bufPrB[16][65], bufPiB[16][65];  // pair-b packed F~0
    // fused coef table [66][8] uints: row p = [cd sd ca2 sa2 sa ca h 0],
    // each uint = duplicated f16 pair; rows 64,65 = zero pad (prefetch target)
    __shared__ __align__(16) unsigned cwl[528];

    // ---- per-block coefficient table (fused, R24) ----
    if (t < NP2) {
        const float tre = theta_re[t], tim = theta_im[t];
        const float a2 = tre * tre + tim * tim;
        const float inva = __frsqrt_rn(a2);        // |theta| >= 0.1
        const float a = a2 * inva;
        const float c = tre * inva, s = tim * inva;   // cos/sin(phi_p)
        float cp = 1.f, sp = 0.f;                     // cos/sin(phi_{p-1})
        if (t > 0) {
            const float ure = theta_re[t - 1], uim = theta_im[t - 1];
            const float ia = __frsqrt_rn(ure * ure + uim * uim);
            cp = ure * ia; sp = uim * ia;
        }
        const float cd = cp * c + sp * s;          // cos(phi_{p-1}-phi_p)
        const float sd = sp * c - cp * s;          // sin(phi_{p-1}-phi_p)
        float sa, ca;
        __sincosf(a, &sa, &ca);
        const float ca2 = 0.5f + 0.5f * ca;        // cos^2(a/2)
        const float sa2 = 0.5f - 0.5f * ca;        // sin^2(a/2)
        unsigned* row = cwl + t * 8;
        const float vals[8] = { cd, sd, ca2, sa2, sa, ca, 0.5f * sa, 0.f };
#pragma unroll
        for (int j = 0; j < 8; ++j) {
            const __half h = __float2half(vals[j]);
            __half2 hp = __halves2half2(h, h);
            unsigned u; __builtin_memcpy(&u, &hp, 4);
            row[j] = u;
        }
    } else if (t < NP2 + 16) {
        cwl[NP2 * 8 + (t - NP2)] = 0u;             // zero pad rows 64,65
    }

    const float tr = TRp[0];
    const float E1A = __expf(-tr / qmaps[V + vA]);
    const float E2A = __expf(-tr / qmaps[2 * V + vA]);
    const float E1B = __expf(-tr / qmaps[V + vB]);
    const float E2B = __expf(-tr / qmaps[2 * V + vB]);
    const float E1C = __expf(-tr / qmaps[V + vC]);
    const float E2C = __expf(-tr / qmaps[2 * V + vC]);
    const float E1D = __expf(-tr / qmaps[V + vD]);
    const float E2D = __expf(-tr / qmaps[2 * V + vD]);
    const bool s0 = (sub == 0);
    const bool s15 = (sub == 15);
    const __half2 pE1a = __floats2half2_rn(E1A, E1B);
    const __half2 pE2a = __floats2half2_rn(E2A, E2B);
    const __half2 pE1b = __floats2half2_rn(E1C, E1D);
    const __half2 pE2b = __floats2half2_rn(E2C, E2D);
    const __half2 zeroH = __floats2half2_rn(0.f, 0.f);
    const __half2 recHa = s0 ? __floats2half2_rn(1.f - E1A, 1.f - E1B) : zeroH;
    const __half2 recHb = s0 ? __floats2half2_rn(1.f - E1C, 1.f - E1D) : zeroH;

    // slot-packed state, 2 voxels per reg (f16 halves), two independent pairs
    __half2 Pr0a = zeroH, Pr1a = zeroH, Pi0a = zeroH, Pi1a = zeroH;
    __half2 Mr0a = zeroH, Mr1a = zeroH, Mi0a = zeroH, Mi1a = zeroH;
    __half2 Zr0a = s0 ? __floats2half2_rn(1.f, 1.f) : zeroH;   // E1*1+(1-E1)=1 exact
    __half2 Zr1a = zeroH, Zi0a = zeroH, Zi1a = zeroH;
    __half2 Pr0b = zeroH, Pr1b = zeroH, Pi0b = zeroH, Pi1b = zeroH;
    __half2 Mr0b = zeroH, Mr1b = zeroH, Mi0b = zeroH, Mi1b = zeroH;
    __half2 Zr0b = s0 ? __floats2half2_rn(1.f, 1.f) : zeroH;
    __half2 Zr1b = zeroH, Zi0b = zeroH, Zi1b = zeroH;

    __syncthreads();                               // coef table ready

    // coefficient stream: broadcast ds_read_b128 pairs, 1-iteration prefetch
    const uint4* __restrict__ cwq = (const uint4*)cwl;
    uint4 q0 = cwq[0], q1 = cwq[1];

    __half2 nPr0a, nPi0a, nMr0a, nMi0a, nPr1a, nPi1a, nMr1a, nMi1a;
    __half2 nPr0b, nPi0b, nMr0b, nMi0b, nPr1b, nPi1b, nMr1b, nMi1b;

    // ---- phase A: p in [0,15), slot1 exactly zero -> slot0 only ----
#pragma unroll 2
    for (int p = 0; p < 15; ++p) {
        const int nb = 2 * (p + 1);
        const uint4 n0 = cwq[nb], n1 = cwq[nb + 1];
        const __half2 cd = u2h(q0.x), sd = u2h(q0.y);
        const __half2 ca2 = u2h(q0.z), sa2 = u2h(q0.w);
        const __half2 sa = u2h(q1.x), ca = u2h(q1.y), hh = u2h(q1.z);
        const __half2 eca = __hmul2(pE2a, cd);
        const __half2 esa = __hmul2(pE2a, sd);
        const __half2 esna = __hneg2(esa);
        const __half2 ecb = __hmul2(pE2b, cd);
        const __half2 esb = __hmul2(pE2b, sd);
        const __half2 esnb = __hneg2(esb);
        slot_mat(Pr0a, Pi0a, Mr0a, Mi0a, Zr0a, Zi0a, eca, esa, esna,
                 ca2, sa2, sa, ca, hh, pE1a, recHa, nPr0a, nPi0a, nMr0a, nMi0a);
        slot_mat(Pr0b, Pi0b, Mr0b, Mi0b, Zr0b, Zi0b, ecb, esb, esnb,
                 ca2, sa2, sa, ca, hh, pE1b, recHb, nPr0b, nPi0b, nMr0b, nMi0b);
        if (s0) {
            bufPrA[vloc][p] = h2u(nPr0a); bufPiA[vloc][p] = h2u(nPi0a);
            bufPrB[vloc][p] = h2u(nPr0b); bufPiB[vloc][p] = h2u(nPi0b);
        }
        const __half2 rPra = rroth<ROR1>(nPr0a);
        const __half2 rPia = rroth<ROR1>(nPi0a);
        const __half2 rMra = rroth<RSHL1>(nMr0a);  // lane i <- i+1; lane15 <- 0
        const __half2 rMia = rroth<RSHL1>(nMi0a);
        const __half2 rPrb = rroth<ROR1>(nPr0b);
        const __half2 rPib = rroth<ROR1>(nPi0b);
        const __half2 rMrb = rroth<RSHL1>(nMr0b);
        const __half2 rMib = rroth<RSHL1>(nMi0b);
        Pr0a = s0 ? rMra : rPra;                   // level0 <- conj(M'_1)
        Pi0a = s0 ? __hneg2(rMia) : rPia;
        Mr0a = rMra;                               // lane15: 0 (exact: M'_16 = 0)
        Mi0a = rMia;
        Pr0b = s0 ? rMrb : rPrb;
        Pi0b = s0 ? __hneg2(rMib) : rPib;
        Mr0b = rMrb;
        Mi0b = rMib;
        q0 = n0; q1 = n1;
    }

    // ---- phase B: p in [15,48), both slots live ----
#pragma unroll 2
    for (int p = 15; p < 48; ++p) {
        const int nb = 2 * (p + 1);
        const uint4 n0 = cwq[nb], n1 = cwq[nb + 1];
        const __half2 cd = u2h(q0.x), sd = u2h(q0.y);
        const __half2 ca2 = u2h(q0.z), sa2 = u2h(q0.w);
        const __half2 sa = u2h(q1.x), ca = u2h(q1.y), hh = u2h(q1.z);
        const __half2 eca = __hmul2(pE2a, cd);
        const __half2 esa = __hmul2(pE2a, sd);
        const __half2 esna = __hneg2(esa);
        const __half2 ecb = __hmul2(pE2b, cd);
        const __half2 esb = __hmul2(pE2b, sd);
        const __half2 esnb = __hneg2(esb);
        slot_mat(Pr0a, Pi0a, Mr0a, Mi0a, Zr0a, Zi0a, eca, esa, esna,
                 ca2, sa2, sa, ca, hh, pE1a, recHa, nPr0a, nPi0a, nMr0a, nMi0a);
        slot_mat(Pr1a, Pi1a, Mr1a, Mi1a, Zr1a, Zi1a, eca, esa, esna,
                 ca2, sa2, sa, ca, hh, pE1a, zeroH, nPr1a, nPi1a, nMr1a, nMi1a);
        slot_mat(Pr0b, Pi0b, Mr0b, Mi0b, Zr0b, Zi0b, ecb, esb, esnb,
                 ca2, sa2, sa, ca, hh, pE1b, recHb, nPr0b, nPi0b, nMr0b, nMi0b);
        slot_mat(Pr1b, Pi1b, Mr1b, Mi1b, Zr1b, Zi1b, ecb, esb, esnb,
                 ca2, sa2, sa, ca, hh, pE1b, zeroH, nPr1b, nPi1b, nMr1b, nMi1b);
        if (s0) {
            bufPrA[vloc][p] = h2u(nPr0a); bufPiA[vloc][p] = h2u(nPi0a);
            bufPrB[vloc][p] = h2u(nPr0b); bufPiB[vloc][p] = h2u(nPi0b);
        }
        const __half2 rPr0a = rroth<ROR1>(nPr0a),  rPr1a = rroth<ROR1>(nPr1a);
        const __half2 rPi0a = rroth<ROR1>(nPi0a),  rPi1a = rroth<ROR1>(nPi1a);
        const __half2 rMr0a = rroth<ROR15>(nMr0a), rMr1a = rroth<ROR15>(nMr1a);
        const __half2 rMi0a = rroth<ROR15>(nMi0a), rMi1a = rroth<ROR15>(nMi1a);
        const __half2 rPr0b = rroth<ROR1>(nPr0b),  rPr1b = rroth<ROR1>(nPr1b);
        const __half2 rPi0b = rroth<ROR1>(nPi0b),  rPi1b = rroth<ROR1>(nPi1b);
        const __half2 rMr0b = rroth<ROR15>(nMr0b), rMr1b = rroth<ROR15>(nMr1b);
        const __half2 rMi0b = rroth<ROR15>(nMi0b), rMi1b = rroth<ROR15>(nMi1b);
        Pr1a = s0 ? rPr0a : rPr1a;                 // level16 <- P'_15
        Pi1a = s0 ? rPi0a : rPi1a;
        Pr0a = s0 ? rMr0a : rPr0a;                 // level0 <- conj(M'_1)
        Pi0a = s0 ? __hneg2(rMi0a) : rPi0a;
        Mr0a = s15 ? rMr1a : rMr0a;                // level15 <- M'_16
        Mi0a = s15 ? rMi1a : rMi0a;
        Mr1a = s15 ? zeroH : rMr1a;                // level31 <- M'_32 = 0 exactly
        Mi1a = s15 ? zeroH : rMi1a;
        Pr1b = s0 ? rPr0b : rPr1b;
        Pi1b = s0 ? rPi0b : rPi1b;
        Pr0b = s0 ? rMr0b : rPr0b;
        Pi0b = s0 ? __hneg2(rMi0b) : rPi0b;
        Mr0b = s15 ? rMr1b : rMr0b;
        Mi0b = s15 ? rMi1b : rMi0b;
        Mr1b = s15 ? zeroH : rMr1b;
        Mi1b = s15 ? zeroH : rMi1b;
        q0 = n0; q1 = n1;
    }

    // ---- phase C: p in [48,64), slot1 in the dead cone -> slot0 only ----
#pragma unroll 2
    for (int p = 48; p < NP2; ++p) {
        const int nb = 2 * (p + 1);
        const uint4 n0 = cwq[nb], n1 = cwq[nb + 1];
        const __half2 cd = u2h(q0.x), sd = u2h(q0.y);
        const __half2 ca2 = u2h(q0.z), sa2 = u2h(q0.w);
        const __half2 sa = u2h(q1.x), ca = u2h(q1.y), hh = u2h(q1.z);
        const __half2 eca = __hmul2(pE2a, cd);
        const __half2 esa = __hmul2(pE2a, sd);
        const __half2 esna = __hneg2(esa);
        const __half2 ecb = __hmul2(pE2b, cd);
        const __half2 esb = __hmul2(pE2b, sd);
        const __half2 esnb = __hneg2(esb);
        slot_mat(Pr0a, Pi0a, Mr0a, Mi0a, Zr0a, Zi0a, eca, esa, esna,
                 ca2, sa2, sa, ca, hh, pE1a, recHa, nPr0a, nPi0a, nMr0a, nMi0a);
        slot_mat(Pr0b, Pi0b, Mr0b, Mi0b, Zr0b, Zi0b, ecb, esb, esnb,
                 ca2, sa2, sa, ca, hh, pE1b, recHb, nPr0b, nPi0b, nMr0b, nMi0b);
        if (s0) {
            bufPrA[vloc][p] = h2u(nPr0a); bufPiA[vloc][p] = h2u(nPi0a);
            bufPrB[vloc][p] = h2u(nPr0b); bufPiB[vloc][p] = h2u(nPi0b);
        }
        const __half2 rPra = rroth<ROR1>(nPr0a);
        const __half2 rPia = rroth<ROR1>(nPi0a);
        const __half2 rMra = rroth<RSHL1>(nMr0a);  // lane15's junk: dead cone
        const __half2 rMia = rroth<RSHL1>(nMi0a);
        const __half2 rPrb = rroth<ROR1>(nPr0b);
        const __half2 rPib = rroth<ROR1>(nPi0b);
        const __half2 rMrb = rroth<RSHL1>(nMr0b);
        const __half2 rMib = rroth<RSHL1>(nMi0b);
        Pr0a = s0 ? rMra : rPra;
        Pi0a = s0 ? __hneg2(rMia) : rPia;
        Mr0a = rMra;
        Mi0a = rMia;
        Pr0b = s0 ? rMrb : rPrb;
        Pi0b = s0 ? __hneg2(rMib) : rPib;
        Mr0b = rMrb;
        Mi0b = rMib;
        q0 = n0; q1 = n1;
    }

    // ---- epilogue: unpack f16 halves, magnitude * PD (f32), coalesced stores ----
    __syncthreads();
    float4* out4 = (float4*)out;
#pragma unroll
    for (int i = 0; i < 4; ++i) {
        const int q = i * 256 + t;
        const int r = q >> 4;              // output voxel row 0..63
        const int c = (q & 15) * 4;        // pulse col
        const int row = r & 15;            // state row
        const bool hi = (r >> 4) & 1;      // which f16 half
        const bool pb = (r >> 5) & 1;      // which pair buffer
        const float PDr = qmaps[base + r];
        float4 val;
        float* vp = &val.x;
#pragma unroll
        for (int j = 0; j < 4; ++j) {
            const unsigned ur = pb ? bufPrB[row][c + j] : bufPrA[row][c + j];
            const unsigned ui = pb ? bufPiB[row][c + j] : bufPiA[row][c + j];
            const __half2 hr = u2h(ur);
            const __half2 hii = u2h(ui);
            const float pr = hi ? __high2float(hr) : __low2float(hr);
            const float pi = hi ? __high2float(hii) : __low2float(hii);
            vp[j] = sqrtf(pr * pr + pi * pi) * PDr;
        }
        out4[blockIdx.x * 1024 + q] = val;
    }
}

extern "C" void kernel_launch(void* const* d_in, const int* in_sizes, int n_in,
                              void* d_out, int out_size, void* d_ws, size_t ws_size,
                              hipStream_t stream) {
    const float* theta_re = (const float*)d_in[0];
    const float* theta_im = (const float*)d_in[1];
    const float* TRp      = (const float*)d_in[2];
    const float* qmaps    = (const float*)d_in[3];
    float* out = (float*)d_out;
    const int V = in_sizes[3] / 3;             // qmaps is [3, V, 1]
    (void)d_ws; (void)ws_size;
    epg_kernel<<<dim3(V / 64), dim3(256), 0, stream>>>(
        theta_re, theta_im, TRp, qmaps, out, V);
}